// Round 2
// baseline (119.160 us; speedup 1.0000x reference)
//
#include <hip/hip_runtime.h>
#include <cstdint>
#include <cstddef>

typedef float f32x4 __attribute__((ext_vector_type(4)));

constexpr int BB = 16, CC = 3, HH = 512, WW = 512;
constexpr int HW = HH * WW;
constexpr float RATIO = 0.12f;

// ws layout: [0..BB) uint min-bits, [BB..2*BB) uint max-bits, img_v at byte 256.
// Values are non-negative floats, so uint bit ordering == float ordering.

__global__ void init_mm(unsigned int* mm) {
    int i = threadIdx.x;
    if (i < BB)            mm[i] = 0x7F800000u;  // +inf  (min identity)
    else if (i < 2 * BB)   mm[i] = 0u;           // 0     (max identity, vals >= 0)
}

__global__ __launch_bounds__(256) void k1_chanmax_minmax(
        const float* __restrict__ img, unsigned int* __restrict__ mm,
        float* __restrict__ imgv) {
    int t    = blockIdx.x * 256 + threadIdx.x;
    int off4 = t << 2;                 // 4 pixels per thread
    int b    = off4 / HW;              // uniform per block (256 blocks/image)
    int off  = off4 - b * HW;
    const f32x4* base = (const f32x4*)(img + (size_t)b * CC * HW + off);
    // img is dead after this kernel: non-temporal loads keep L2/L3 for imgv/out.
    f32x4 c0 = __builtin_nontemporal_load(base);
    f32x4 c1 = __builtin_nontemporal_load(base + HW / 4);
    f32x4 c2 = __builtin_nontemporal_load(base + 2 * (HW / 4));
    f32x4 v;
    v.x = fmaxf(fmaxf(c0.x, c1.x), c2.x);
    v.y = fmaxf(fmaxf(c0.y, c1.y), c2.y);
    v.z = fmaxf(fmaxf(c0.z, c1.z), c2.z);
    v.w = fmaxf(fmaxf(c0.w, c1.w), c2.w);
    // cached store: k2 re-reads imgv, keep it in L2/L3
    *(f32x4*)(imgv + (size_t)b * HW + off) = v;

    float mn = fminf(fminf(v.x, v.y), fminf(v.z, v.w));
    float mx = fmaxf(fmaxf(v.x, v.y), fmaxf(v.z, v.w));
    #pragma unroll
    for (int s = 32; s > 0; s >>= 1) {
        mn = fminf(mn, __shfl_xor(mn, s, 64));
        mx = fmaxf(mx, __shfl_xor(mx, s, 64));
    }
    __shared__ float smn[4], smx[4];
    int wave = threadIdx.x >> 6;
    if ((threadIdx.x & 63) == 0) { smn[wave] = mn; smx[wave] = mx; }
    __syncthreads();
    if (threadIdx.x == 0) {
        float m0 = fminf(fminf(smn[0], smn[1]), fminf(smn[2], smn[3]));
        float m1 = fmaxf(fmaxf(smx[0], smx[1]), fmaxf(smx[2], smx[3]));
        atomicMin(&mm[b],      __float_as_uint(m0));
        atomicMax(&mm[BB + b], __float_as_uint(m1));
    }
}

__device__ inline void load_row(const float* __restrict__ imgv,
                                int b, int hh, int c, float v[6]) {
    const float* base = imgv + (size_t)b * HW + hh * WW;
    v[0] = base[max(c - 1, 0)];
    f32x4 q = *(const f32x4*)(base + c);
    v[1] = q.x; v[2] = q.y; v[3] = q.z; v[4] = q.w;
    v[5] = base[min(c + 4, WW - 1)];
}

__global__ __launch_bounds__(256) void k2_edges(
        const float* __restrict__ imgv,
        const unsigned int* __restrict__ mm, float* __restrict__ out) {
    int t = blockIdx.x * 256 + threadIdx.x;
    int r = t >> 7;             // row index over B*H (128 vec4-cols per row)
    int c = (t & 127) << 2;     // column base (multiple of 4 -> aligned float4)
    int b = r / HH;
    int h = r - b * HH;
    float thr = (__uint_as_float(mm[BB + b]) - __uint_as_float(mm[b])) * RATIO;
    int hm = max(h - 1, 0), hp = min(h + 1, HH - 1);

    float vt[6], vm[6], vp[6];
    load_row(imgv, b, hm, c, vt);
    load_row(imgv, b, h,  c, vm);
    load_row(imgv, b, hp, c, vp);

    // v[k] holds column (c + k - 1), rows clamped.  For pixel i and stencil
    // (px,py): row = {0:vt,1:vm,2:vp}[px], index = i + py.
    float d[8][4];
    #pragma unroll
    for (int i = 0; i < 4; ++i) {
        d[0][i] = vm[i]     - vp[i + 2];   // (1,0)-(2,2)
        d[1][i] = vt[i + 2] - vm[i];       // (0,2)-(1,0)
        d[2][i] = vp[i + 1] - vt[i + 2];   // (2,1)-(0,2)
        d[3][i] = vt[i]     - vp[i + 1];   // (0,0)-(2,1)
        d[4][i] = vm[i + 2] - vm[i + 1];   // (1,2)-(1,1)
        d[5][i] = vt[i + 1] - vm[i + 1];   // (0,1)-(1,1)
        d[6][i] = vt[i + 2] - vm[i + 1];   // (0,2)-(1,1)
        d[7][i] = vt[i]     - vm[i + 1];   // (0,0)-(1,1)
    }
    size_t pixoff = (size_t)h * WW + c;
    #pragma unroll
    for (int f = 0; f < 8; ++f) {
        f32x4 qp, qn;
        #pragma unroll
        for (int i = 0; i < 4; ++i) {
            float df  = d[f][i];
            float pos = fmaxf(df, 0.0f);
            float neg = fmaxf(-df, 0.0f);
            ((float*)&qp)[i] = (pos >= thr) ? 1.0f : 0.0f;
            ((float*)&qn)[i] = (neg >= thr) ? 1.0f : 0.0f;
        }
        size_t plane = (size_t)(f * BB + b) * 2;
        // non-temporal: write-once data, avoid L2 allocate/pollution
        __builtin_nontemporal_store(qp, (f32x4*)(out + (plane)     * HW + pixoff));
        __builtin_nontemporal_store(qn, (f32x4*)(out + (plane + 1) * HW + pixoff));
    }
}

extern "C" void kernel_launch(void* const* d_in, const int* in_sizes, int n_in,
                              void* d_out, int out_size, void* d_ws, size_t ws_size,
                              hipStream_t stream) {
    const float* img = (const float*)d_in[0];
    float* out = (float*)d_out;
    unsigned int* mm = (unsigned int*)d_ws;
    float* imgv = (float*)((char*)d_ws + 256);

    init_mm<<<1, 64, 0, stream>>>(mm);
    int blocks = BB * HW / (256 * 4);   // 4096
    k1_chanmax_minmax<<<blocks, 256, 0, stream>>>(img, mm, imgv);
    k2_edges<<<blocks, 256, 0, stream>>>(imgv, mm, out);
}